// Round 2
// baseline (5027.541 us; speedup 1.0000x reference)
//
#include <hip/hip_runtime.h>
#include <cstdint>

typedef __attribute__((ext_vector_type(8))) short bf16x8;
typedef __attribute__((ext_vector_type(4))) float f32x4;

__device__ __forceinline__ float bf2f(unsigned short u) {
  union { unsigned int i; float f; } v;
  v.i = ((unsigned int)u) << 16;
  return v.f;
}
__device__ __forceinline__ unsigned short f2bf(float f) {
  union { float f; unsigned int i; } v;
  v.f = f;
  unsigned int x = v.i;
  return (unsigned short)((x + 0x7FFFu + ((x >> 16) & 1u)) >> 16);
}

// ---------------- P0: copy initial hidden state ----------------
__global__ __launch_bounds__(256) void k_init_h(const float* __restrict__ hidden,
                                                float* __restrict__ h0buf,
                                                float* __restrict__ h1buf) {
  int i = blockIdx.x * 256 + threadIdx.x;  // 32768 total
  if (i < 16384) h0buf[i] = hidden[i];
  else h1buf[i - 16384] = hidden[i];
}

// ---------------- P1: encoder_outputs -> bf16 copy ----------------
__global__ __launch_bounds__(256) void k_cvt_enc(const float* __restrict__ enc,
                                                 unsigned short* __restrict__ encb) {
  int i = (blockIdx.x * 256 + threadIdx.x) * 4;  // 4194304 total
  float4 v = *(const float4*)(enc + i);
  ushort4 o;
  o.x = f2bf(v.x); o.y = f2bf(v.y); o.z = f2bf(v.z); o.w = f2bf(v.w);
  *(ushort4*)(encb + i) = o;
}

// ---------------- P2: encW_T[b][h][s] = sum_e enc[b][s][e] * Wa[e][h] ----------------
// grid 512 = 32 b * 16 s-chunks (8 s each), 256 threads (each owns h=tid and h=tid+256)
__global__ __launch_bounds__(256) void k_encwt(const float* __restrict__ enc,
                                               const float* __restrict__ Wa,
                                               unsigned short* __restrict__ encwt) {
  __shared__ float esh[8 * 1024];  // 32 KB
  int tid = threadIdx.x;
  int b = blockIdx.x >> 4;
  int s0 = (blockIdx.x & 15) * 8;
  for (int u = 0; u < 32; u++) {
    int f = u * 256 + tid;  // 8192 floats
    esh[f] = enc[((size_t)b * 128 + s0 + (f >> 10)) * 1024 + (f & 1023)];
  }
  __syncthreads();
  float acc0[8] = {}, acc1[8] = {};
  for (int e = 0; e < 1024; e++) {
    float w0 = Wa[e * 512 + tid];
    float w1 = Wa[e * 512 + tid + 256];
#pragma unroll
    for (int si = 0; si < 8; si++) {
      float ev = esh[si * 1024 + e];  // broadcast
      acc0[si] += w0 * ev;
      acc1[si] += w1 * ev;
    }
  }
#pragma unroll
  for (int si = 0; si < 8; si++) {
    encwt[((size_t)b * 512 + tid) * 128 + s0 + si] = f2bf(acc0[si]);
    encwt[((size_t)b * 512 + tid + 256) * 128 + s0 + si] = f2bf(acc1[si]);
  }
}

// ---------------- per-step attention ----------------
// grid 32 (one block per batch b), 256 threads
__global__ __launch_bounds__(256) void k_attn(
    const float* __restrict__ h1prev,          // [32][512]
    const unsigned short* __restrict__ encwt,  // [32][512][128] bf16
    const unsigned short* __restrict__ encb,   // [32][128][1024] bf16
    const int* __restrict__ mask,              // [32][128] int32 (bool -> int)
    const float* __restrict__ embedding,       // [32000][512]
    const int* __restrict__ tgt,               // [32][64]
    float* __restrict__ x0b,                   // [32][1536] = [emb | ctx]
    unsigned short* __restrict__ states,       // [2048][1536] bf16
    int t) {
  __shared__ float h1sh[512];
  __shared__ float rsh[256];
  __shared__ float ssh[128];
  __shared__ float red2[128];
  int tid = threadIdx.x;
  int b = blockIdx.x;
  h1sh[tid] = h1prev[b * 512 + tid];
  h1sh[tid + 256] = h1prev[b * 512 + tid + 256];
  __syncthreads();
  // scores[s] = sum_h h1[h] * encW_T[b][h][s]   (split over h halves)
  int s = tid & 127, part = tid >> 7;
  const unsigned short* ew = encwt + ((size_t)b * 512 + part * 256) * 128 + s;
  float pacc = 0.f;
#pragma unroll 4
  for (int h = 0; h < 256; h++)
    pacc += bf2f(ew[h * 128]) * h1sh[part * 256 + h];
  rsh[tid] = pacc;
  __syncthreads();
  if (tid < 128) {
    float sc = (rsh[tid] + rsh[tid + 128]) * 0.03125f;  // 1/sqrt(1024)
    if (mask[b * 128 + tid] == 0) sc = -__builtin_huge_valf();
    ssh[tid] = sc;
    red2[tid] = sc;
  }
  __syncthreads();
  for (int st = 64; st > 0; st >>= 1) {
    if (tid < st) red2[tid] = fmaxf(red2[tid], red2[tid + st]);
    __syncthreads();
  }
  float mx = red2[0];
  __syncthreads();
  if (tid < 128) {
    float e = __expf(ssh[tid] - mx);
    ssh[tid] = e;
    red2[tid] = e;
  }
  __syncthreads();
  for (int st = 64; st > 0; st >>= 1) {
    if (tid < st) red2[tid] += red2[tid + st];
    __syncthreads();
  }
  float inv = 1.f / red2[0];
  __syncthreads();
  if (tid < 128) ssh[tid] *= inv;
  __syncthreads();
  // ctx[e0..e0+3] = sum_s attn[s] * enc[b][s][e]
  int e0 = tid * 4;
  float c0 = 0.f, c1 = 0.f, c2 = 0.f, c3 = 0.f;
  const unsigned short* eb = encb + (size_t)b * 131072 + e0;
  for (int s2 = 0; s2 < 128; s2++) {
    float a = ssh[s2];
    ushort4 ev = *(const ushort4*)(eb + s2 * 1024);
    c0 += a * bf2f(ev.x);
    c1 += a * bf2f(ev.y);
    c2 += a * bf2f(ev.z);
    c3 += a * bf2f(ev.w);
  }
  float4 cv;
  cv.x = c0; cv.y = c1; cv.z = c2; cv.w = c3;
  *(float4*)(x0b + b * 1536 + 512 + e0) = cv;
  ushort4 sv;
  sv.x = f2bf(c0); sv.y = f2bf(c1); sv.z = f2bf(c2); sv.w = f2bf(c3);
  *(ushort4*)(states + (size_t)(t * 32 + b) * 1536 + 512 + e0) = sv;
  // embedding gather into x0[0:512]
  int tok = tgt[b * 64 + t];
  x0b[b * 1536 + tid] = embedding[(size_t)tok * 512 + tid];
  x0b[b * 1536 + tid + 256] = embedding[(size_t)tok * 512 + tid + 256];
}

// ---------------- per-step GRU cell (both layers) ----------------
// grid 256 (2 output features each), 256 threads: tid = kq*64 + jl*32 + b
__global__ __launch_bounds__(256) void k_gru(
    const float* __restrict__ x,  // [32][xK]
    int xK,                       // 1536 (layer0) or 512 (layer1)
    const float* __restrict__ hprev,  // [32][512]
    const float* __restrict__ w_ih,   // [1536][xK]
    const float* __restrict__ w_hh,   // [1536][512]
    const float* __restrict__ b_ih, const float* __restrict__ b_hh,
    float* __restrict__ hout,             // [32][512]
    unsigned short* __restrict__ states,  // or nullptr
    int srow) {
  __shared__ float xsh[32 * 257];  // padded: bank = (b + k) % 32, conflict-free
  __shared__ float red[256 * 4];
  int tid = threadIdx.x;
  int b = tid & 31;
  int jl = (tid >> 5) & 1;
  int kq = tid >> 6;
  int j = blockIdx.x * 2 + jl;
  int kb = kq * 64;
  float gr = 0.f, gz = 0.f, gin = 0.f, ghn = 0.f;
  // input-hidden part
  for (int t0 = 0; t0 < xK; t0 += 256) {
    for (int u = 0; u < 32; u++)
      xsh[u * 257 + tid] = x[u * xK + t0 + tid];
    __syncthreads();
    {
      const float4* w0p = (const float4*)(w_ih + (size_t)j * xK + t0 + kb);
      const float4* w1p = (const float4*)(w_ih + (size_t)(j + 512) * xK + t0 + kb);
      const float4* w2p = (const float4*)(w_ih + (size_t)(j + 1024) * xK + t0 + kb);
      const float* xr = xsh + b * 257 + kb;
#pragma unroll 4
      for (int k4 = 0; k4 < 16; k4++) {
        float4 wa = w0p[k4], wb = w1p[k4], wc = w2p[k4];
        float xv0 = xr[k4 * 4 + 0], xv1 = xr[k4 * 4 + 1];
        float xv2 = xr[k4 * 4 + 2], xv3 = xr[k4 * 4 + 3];
        gr = fmaf(wa.x, xv0, gr); gr = fmaf(wa.y, xv1, gr);
        gr = fmaf(wa.z, xv2, gr); gr = fmaf(wa.w, xv3, gr);
        gz = fmaf(wb.x, xv0, gz); gz = fmaf(wb.y, xv1, gz);
        gz = fmaf(wb.z, xv2, gz); gz = fmaf(wb.w, xv3, gz);
        gin = fmaf(wc.x, xv0, gin); gin = fmaf(wc.y, xv1, gin);
        gin = fmaf(wc.z, xv2, gin); gin = fmaf(wc.w, xv3, gin);
      }
    }
    __syncthreads();
  }
  // hidden-hidden part
  for (int t0 = 0; t0 < 512; t0 += 256) {
    for (int u = 0; u < 32; u++)
      xsh[u * 257 + tid] = hprev[u * 512 + t0 + tid];
    __syncthreads();
    {
      const float4* w0p = (const float4*)(w_hh + (size_t)j * 512 + t0 + kb);
      const float4* w1p = (const float4*)(w_hh + (size_t)(j + 512) * 512 + t0 + kb);
      const float4* w2p = (const float4*)(w_hh + (size_t)(j + 1024) * 512 + t0 + kb);
      const float* xr = xsh + b * 257 + kb;
#pragma unroll 4
      for (int k4 = 0; k4 < 16; k4++) {
        float4 wa = w0p[k4], wb = w1p[k4], wc = w2p[k4];
        float xv0 = xr[k4 * 4 + 0], xv1 = xr[k4 * 4 + 1];
        float xv2 = xr[k4 * 4 + 2], xv3 = xr[k4 * 4 + 3];
        gr = fmaf(wa.x, xv0, gr); gr = fmaf(wa.y, xv1, gr);
        gr = fmaf(wa.z, xv2, gr); gr = fmaf(wa.w, xv3, gr);
        gz = fmaf(wb.x, xv0, gz); gz = fmaf(wb.y, xv1, gz);
        gz = fmaf(wb.z, xv2, gz); gz = fmaf(wb.w, xv3, gz);
        ghn = fmaf(wc.x, xv0, ghn); ghn = fmaf(wc.y, xv1, ghn);
        ghn = fmaf(wc.z, xv2, ghn); ghn = fmaf(wc.w, xv3, ghn);
      }
    }
    __syncthreads();
  }
  red[tid * 4 + 0] = gr;
  red[tid * 4 + 1] = gz;
  red[tid * 4 + 2] = gin;
  red[tid * 4 + 3] = ghn;
  __syncthreads();
  if (tid < 64) {
#pragma unroll
    for (int g = 1; g < 4; g++) {
      gr += red[(tid + g * 64) * 4 + 0];
      gz += red[(tid + g * 64) * 4 + 1];
      gin += red[(tid + g * 64) * 4 + 2];
      ghn += red[(tid + g * 64) * 4 + 3];
    }
    gr += b_ih[j] + b_hh[j];
    gz += b_ih[j + 512] + b_hh[j + 512];
    gin += b_ih[j + 1024];
    ghn += b_hh[j + 1024];
    float r = 1.f / (1.f + __expf(-gr));
    float zz = 1.f / (1.f + __expf(-gz));
    float nv = gin + r * ghn;
    float e2 = __expf(-2.f * fabsf(nv));
    float th = (1.f - e2) / (1.f + e2);
    th = copysignf(th, nv);
    float hp = hprev[b * 512 + j];
    float hn = (1.f - zz) * th + zz * hp;
    hout[b * 512 + j] = hn;
    if (states) states[(size_t)(srow + b) * 1536 + j] = f2bf(hn);
  }
}

// ---------------- batched logits GEMM: [2016x1536] @ fc_w.T [1536x32000] ----------------
// grid 4000 = 16 m-tiles * 250 n-tiles, 256 threads, 128x128 C tile, bf16 MFMA
__global__ __launch_bounds__(256) void k_gemm(
    const unsigned short* __restrict__ states,  // [2048][1536] bf16
    const float* __restrict__ fc_w,             // [32000][1536]
    const float* __restrict__ fc_b,             // [32000]
    float* __restrict__ out) {                  // [32][63][32000]
  __shared__ unsigned short Ash[128 * 40];  // [m][k], pad 40 -> 2-way-free banks
  __shared__ unsigned short Bsh[128 * 40];  // [n][k]
  int tid = threadIdx.x;
  int bx = blockIdx.x;
  int m0 = (bx & 15) * 128;
  int n0 = (bx >> 4) * 128;
  int lane = tid & 63, wave = tid >> 6;
  int q = lane >> 4, l16 = lane & 15;
  int wrow = (wave >> 1) * 64, wcol = (wave & 1) * 64;
  int arow = tid >> 1, ahalf = tid & 1;
  f32x4 acc[4][4] = {};
  const unsigned short* ag = states + (size_t)(m0 + arow) * 1536 + ahalf * 16;
  const float* bg = fc_w + (size_t)(n0 + arow) * 1536 + ahalf * 16;
  for (int k0 = 0; k0 < 1536; k0 += 32) {
    {  // stage A (already bf16)
      const int4* src = (const int4*)(ag + k0);
      int4* dst = (int4*)(Ash + arow * 40 + ahalf * 16);
      dst[0] = src[0];
      dst[1] = src[1];
    }
    {  // stage B (fp32 -> bf16)
      const float4* src = (const float4*)(bg + k0);
      __align__(16) unsigned short us[16];
#pragma unroll
      for (int i = 0; i < 4; i++) {
        float4 v = src[i];
        us[i * 4 + 0] = f2bf(v.x);
        us[i * 4 + 1] = f2bf(v.y);
        us[i * 4 + 2] = f2bf(v.z);
        us[i * 4 + 3] = f2bf(v.w);
      }
      int4* dst = (int4*)(Bsh + arow * 40 + ahalf * 16);
      dst[0] = ((int4*)us)[0];
      dst[1] = ((int4*)us)[1];
    }
    __syncthreads();
    bf16x8 av[4], bv[4];
#pragma unroll
    for (int i = 0; i < 4; i++) {
      av[i] = *(const bf16x8*)(Ash + (wrow + i * 16 + l16) * 40 + q * 8);
      bv[i] = *(const bf16x8*)(Bsh + (wcol + i * 16 + l16) * 40 + q * 8);
    }
#pragma unroll
    for (int mi = 0; mi < 4; mi++)
#pragma unroll
      for (int ni = 0; ni < 4; ni++)
        acc[mi][ni] = __builtin_amdgcn_mfma_f32_16x16x32_bf16(av[mi], bv[ni], acc[mi][ni], 0, 0, 0);
    __syncthreads();
  }
  float fb[4];
#pragma unroll
  for (int ni = 0; ni < 4; ni++) fb[ni] = fc_b[n0 + wcol + ni * 16 + l16];
#pragma unroll
  for (int mi = 0; mi < 4; mi++) {
#pragma unroll
    for (int r = 0; r < 4; r++) {
      int grow = m0 + wrow + mi * 16 + q * 4 + r;  // global state row = t*32 + b
      if (grow < 2016) {
        int tt = grow >> 5, bb = grow & 31;
        float* op = out + (size_t)bb * 2016000 + (size_t)tt * 32000 + n0 + wcol;
#pragma unroll
        for (int ni = 0; ni < 4; ni++)
          op[ni * 16 + l16] = acc[mi][ni][r] + fb[ni];
      }
    }
  }
}

extern "C" void kernel_launch(void* const* d_in, const int* in_sizes, int n_in,
                              void* d_out, int out_size, void* d_ws, size_t ws_size,
                              hipStream_t stream) {
  const int* tgt = (const int*)d_in[0];
  const float* hidden = (const float*)d_in[1];
  const float* enc = (const float*)d_in[2];
  const int* mask = (const int*)d_in[3];
  const float* embedding = (const float*)d_in[4];
  const float* Wa = (const float*)d_in[5];
  const float* w_ih0 = (const float*)d_in[6];
  const float* w_hh0 = (const float*)d_in[7];
  const float* b_ih0 = (const float*)d_in[8];
  const float* b_hh0 = (const float*)d_in[9];
  const float* w_ih1 = (const float*)d_in[10];
  const float* w_hh1 = (const float*)d_in[11];
  const float* b_ih1 = (const float*)d_in[12];
  const float* b_hh1 = (const float*)d_in[13];
  const float* fc_w = (const float*)d_in[14];
  const float* fc_b = (const float*)d_in[15];
  float* out = (float*)d_out;
  char* ws = (char*)d_ws;

  float* h0buf = (float*)(ws + 0);                        // [2][32][512] f32
  float* h1buf = (float*)(ws + 131072);                   // [2][32][512] f32
  float* x0b = (float*)(ws + 262144);                     // [32][1536] f32
  unsigned short* encb = (unsigned short*)(ws + 458752);  // [32][128][1024] bf16
  unsigned short* encwt = (unsigned short*)(ws + 8847360);   // [32][512][128] bf16
  unsigned short* states = (unsigned short*)(ws + 13041664); // [2048][1536] bf16

  k_init_h<<<128, 256, 0, stream>>>(hidden, h0buf, h1buf);
  k_cvt_enc<<<4096, 256, 0, stream>>>(enc, encb);
  k_encwt<<<512, 256, 0, stream>>>(enc, Wa, encwt);

  for (int t = 0; t < 63; t++) {
    int rd = t & 1, wr = rd ^ 1;
    k_attn<<<32, 256, 0, stream>>>(h1buf + rd * 16384, encwt, encb, mask,
                                   embedding, tgt, x0b, states, t);
    k_gru<<<256, 256, 0, stream>>>(x0b, 1536, h0buf + rd * 16384, w_ih0, w_hh0,
                                   b_ih0, b_hh0, h0buf + wr * 16384,
                                   (unsigned short*)nullptr, 0);
    k_gru<<<256, 256, 0, stream>>>(h0buf + wr * 16384, 512, h1buf + rd * 16384,
                                   w_ih1, w_hh1, b_ih1, b_hh1, h1buf + wr * 16384,
                                   states, t * 32);
  }

  k_gemm<<<4000, 256, 0, stream>>>(states, fc_w, fc_b, out);
}